// Round 3
// baseline (2362.592 us; speedup 1.0000x reference)
//
#include <hip/hip_runtime.h>
#include <cstdint>

// ---------------------------------------------------------------------------
// MaskedDeepRNN fused v3: 2-layer masked LSTM, B=64 T=512 D_IN=256 H=512.
// Single persistent kernel, 512 WGs (2/CU): blocks 0..255 layer 0,
// 256..511 layer 1. Islands of 32 WGs per 8-batch slice (blockIdx&7).
// v3 change: h exchange is SELF-VALIDATING — each h pair is one atomic
// 8-byte word {2 x f16, step tag}. Consumers spin on the data itself
// (one L3 hop), no drain-then-flag chain. Flags remain only as lagged
// back-pressure (ring overwrite safety), verified off the critical path.
// Own-WG h units short-circuit through LDS.
// ---------------------------------------------------------------------------

typedef _Float16 f16;
typedef _Float16 half8 __attribute__((ext_vector_type(8)));
typedef _Float16 half4v __attribute__((ext_vector_type(4)));
typedef float floatx4 __attribute__((ext_vector_type(4)));
typedef unsigned long long u64;

#define B_ 64
#define T_ 512
#define DIN_ 256
#define H_ 512
#define G_ 2048

// workspace layout (bytes)
static const size_t OFF_FLAGS = 0;                              // 2x8x32 flags x 64B = 32 KB
static const size_t OFF_H0B   = 32768;                          // 8 isl x 4 slots x 2048 u64 = 512 KB
static const size_t OFF_H1B   = OFF_H0B + 524288;               // 512 KB
static const size_t OFF_WIH0  = OFF_H1B + 524288;
static const size_t OFF_WHH0  = OFF_WIH0 + (size_t)G_ * DIN_ * 2;
static const size_t OFF_WIH1  = OFF_WHH0 + (size_t)G_ * H_ * 2;
static const size_t OFF_WHH1  = OFF_WIH1 + (size_t)G_ * H_ * 2;
static const size_t OFF_B0    = OFF_WHH1 + (size_t)G_ * H_ * 2;
static const size_t OFF_B1    = OFF_B0 + 8192;
static const size_t ZERO_BYTES = OFF_WIH0;                      // flags + rings

__device__ __forceinline__ uint32_t ald(const uint32_t* p) {
    return __hip_atomic_load(p, __ATOMIC_RELAXED, __HIP_MEMORY_SCOPE_AGENT);
}
__device__ __forceinline__ void ast(uint32_t* p, uint32_t v) {
    __hip_atomic_store(p, v, __ATOMIC_RELAXED, __HIP_MEMORY_SCOPE_AGENT);
}
__device__ __forceinline__ u64 ald64(const u64* p) {
    return __hip_atomic_load(p, __ATOMIC_RELAXED, __HIP_MEMORY_SCOPE_AGENT);
}
__device__ __forceinline__ void ast64(u64* p, u64 v) {
    __hip_atomic_store(p, v, __ATOMIC_RELAXED, __HIP_MEMORY_SCOPE_AGENT);
}

// ---------------------------------------------------------------- prep ------
__global__ void k_maskw(const float* __restrict__ w, const float* __restrict__ m,
                        f16* __restrict__ o, int n4) {
    int i = blockIdx.x * 256 + threadIdx.x;
    if (i < n4) {
        const float4 wv = ((const float4*)w)[i];
        const float4 mv = ((const float4*)m)[i];
        half4v h = { (f16)(wv.x * mv.x), (f16)(wv.y * mv.y),
                     (f16)(wv.z * mv.z), (f16)(wv.w * mv.w) };
        ((half4v*)o)[i] = h;
    }
}

__global__ void k_bias(const float* __restrict__ a, const float* __restrict__ b,
                       float* __restrict__ o) {
    int i = blockIdx.x * 256 + threadIdx.x;
    if (i < G_) o[i] = a[i] + b[i];
}

// ------------------------------------------------------------ helpers -------
__device__ __forceinline__ float lstm_cell(float gi, float gf, float gg, float go,
                                           float& c) {
    const float i_ = 1.f / (1.f + __expf(-gi));
    const float f_ = 1.f / (1.f + __expf(-gf));
    const float gc = fminf(fmaxf(gg, -20.f), 20.f);
    const float e2 = __expf(2.f * gc);
    const float g_ = (e2 - 1.f) / (e2 + 1.f);
    const float o_ = 1.f / (1.f + __expf(-go));
    c = f_ * c + i_ * g_;
    const float cc  = fminf(fmaxf(c, -20.f), 20.f);
    const float e2c = __expf(2.f * cc);
    return o_ * (e2c - 1.f) / (e2c + 1.f);
}

__device__ __forceinline__ u64 pack_h(float hn, float ho, uint32_t tag) {
    union { f16 h[2]; uint32_t u; } pk;
    pk.h[0] = (f16)hn; pk.h[1] = (f16)ho;
    return (u64)pk.u | ((u64)tag << 32);
}

// -------------------------------------------------------- fused kernel ------
__global__ __launch_bounds__(256, 2) void fused_rnn(
    const float* __restrict__ x,
    const f16* __restrict__ Wih0, const f16* __restrict__ Whh0,
    const float* __restrict__ bs0,
    const f16* __restrict__ Wih1, const f16* __restrict__ Whh1,
    const float* __restrict__ bs1,
    float* __restrict__ dout,
    u64* __restrict__ h0b,           // [8 isl][4 slots][32 seg][64] {pair,tag}
    u64* __restrict__ h1b,           // same
    uint32_t* __restrict__ flags)    // [2 lay][8 isl][32 x 16 dw] back-pressure
{
    __shared__ f16 bl0[8][520];            // B-operand: own-layer h
    __shared__ f16 bl1[8][520];            // B-operand: x (L0) or h0 (L1)
    __shared__ float glp[4][4][16][9];     // [kquarter][gate][jj][b] partials

    const int tid  = threadIdx.x;
    const int bid  = blockIdx.x;
    const int isl  = bid & 7;              // -> XCD under round-robin
    const int mem  = (bid >> 3) & 31;
    const int layer = bid >> 8;
    const int jb = mem * 16, b0 = isl * 8;
    const int wave = tid >> 6, lane = tid & 63, lm = lane & 15, quad = lane >> 4;
    const int eb = tid >> 4, ejj = tid & 15;
    const int hrow = lm < 8 ? lm : 7;      // cols 8..15 duplicate row 7 (discarded)

    uint32_t* ownF   = flags + (size_t)(layer * 8 + isl) * 512;
    uint32_t* crossF = flags + (size_t)((1 - layer) * 8 + isl) * 512;
    uint32_t* myF    = ownF + mem * 16;
    u64* h0i = h0b + (size_t)isl * 4 * 2048;
    u64* h1i = h1b + (size_t)isl * 4 * 2048;

    // back-pressure flag pointer per wave0 lane
    const uint32_t* fp;
    if (layer == 0) fp = (lane < 32) ? ownF + (size_t)lane * 16
                                     : crossF + (size_t)(lane - 32) * 16;
    else            fp = ownF + (size_t)(lane & 31) * 16;

    // init own-segment of bl0 to h[-1] = 0
    if (tid < 128) bl0[eb][jb + ejj] = (f16)0.f;

    if (layer == 0) {
        // ---- persistent A fragments: Whh0 (K=512) + Wih0 (K=256)
        half8 ah[4][4], ai[4][2];
        {
            const int kb  = wave * 128 + quad * 8;
            const int kbx = wave * 64 + quad * 8;
#pragma unroll
            for (int gt = 0; gt < 4; ++gt) {
                const f16* wr = Whh0 + (size_t)(gt * 512 + jb + lm) * H_ + kb;
                const f16* xr = Wih0 + (size_t)(gt * 512 + jb + lm) * DIN_ + kbx;
#pragma unroll
                for (int kk = 0; kk < 4; ++kk) ah[gt][kk] = *(const half8*)(wr + kk * 32);
#pragma unroll
                for (int kk = 0; kk < 2; ++kk) ai[gt][kk] = *(const half8*)(xr + kk * 32);
            }
        }
        float bias[4];
#pragma unroll
        for (int g = 0; g < 4; ++g) bias[g] = bs0[g * 512 + jb + ejj];
        float c = 0.f;
        const float* xp = x + (size_t)(b0 + (tid >> 5)) * T_ * DIN_ + (tid & 31) * 8;
        float4 xa = *(const float4*)xp;
        float4 xb = *(const float4*)(xp + 4);

        for (int t = 0; t < T_; ++t) {
            // back-pressure preload (verified after MFMA; normally no spin)
            uint32_t fv = 0;
            if (wave == 0) fv = ald(fp);
            // ---- stage h0[t-1] (tag == t) from ring slot (t-1)&3
            const u64* sp = h0i + (size_t)((t + 3) & 3) * 2048;
            u64 v[8];
#pragma unroll
            for (int i = 0; i < 8; ++i) v[i] = ald64(sp + i * 256 + tid);
            // x[t] into bl1; prefetch x[t+1]
            {
                half8 hx = { (f16)xa.x, (f16)xa.y, (f16)xa.z, (f16)xa.w,
                             (f16)xb.x, (f16)xb.y, (f16)xb.z, (f16)xb.w };
                *(half8*)&bl1[tid >> 5][(tid & 31) * 8] = hx;
                const size_t tn = (size_t)(t + 1 < T_ ? t + 1 : t) * DIN_;
                xa = *(const float4*)(xp + tn);
                xb = *(const float4*)(xp + tn + 4);
            }
            const uint32_t expt = (uint32_t)t;
#pragma unroll
            for (int i = 0; i < 8; ++i) {
                const int f = i * 256 + tid;
                if ((f >> 6) != mem) {                 // own seg短: via LDS
                    while ((uint32_t)(v[i] >> 32) != expt) v[i] = ald64(sp + f);
                    *(uint32_t*)&bl0[(f >> 3) & 7][((f >> 6) << 4) + ((f & 7) << 1)]
                        = (uint32_t)v[i];
                }
            }
            __syncthreads();
            if (tid == 0) ast(myF, (uint32_t)(t + 1));   // consumed step-t inputs
            // ---- MFMA: gates = h.Whh (16) + x.Wih (8)
            floatx4 acc[4] = {};
            {
                const f16* br0 = &bl0[hrow][wave * 128 + quad * 8];
                const f16* br1 = &bl1[hrow][wave * 64 + quad * 8];
#pragma unroll
                for (int kk = 0; kk < 4; ++kk) {
                    const half8 bv = *(const half8*)(br0 + kk * 32);
#pragma unroll
                    for (int gt = 0; gt < 4; ++gt)
                        acc[gt] = __builtin_amdgcn_mfma_f32_16x16x32_f16(
                            ah[gt][kk], bv, acc[gt], 0, 0, 0);
                }
#pragma unroll
                for (int kk = 0; kk < 2; ++kk) {
                    const half8 bv = *(const half8*)(br1 + kk * 32);
#pragma unroll
                    for (int gt = 0; gt < 4; ++gt)
                        acc[gt] = __builtin_amdgcn_mfma_f32_16x16x32_f16(
                            ai[gt][kk], bv, acc[gt], 0, 0, 0);
                }
            }
            if (lm < 8)
#pragma unroll
                for (int gt = 0; gt < 4; ++gt)
#pragma unroll
                    for (int r = 0; r < 4; ++r)
                        glp[wave][gt][quad * 4 + r][lm] = acc[gt][r];
            // ---- back-pressure verify: L0 peers >= t-2, L1 partners >= t-3
            if (wave == 0) {
                const int ti = (lane < 32) ? t - 2 : t - 3;
                const uint32_t tgt = ti < 0 ? 0u : (uint32_t)ti;
                while (!__all((int)(fv >= tgt))) fv = ald(fp);
            }
            __syncthreads();
            // ---- gate math + publish h0[t] (tag t+1) into ring slot t&3
            if (tid < 128) {
                float gi = bias[0], gf = bias[1], gg = bias[2], go = bias[3];
#pragma unroll
                for (int w = 0; w < 4; ++w) {
                    gi += glp[w][0][ejj][eb]; gf += glp[w][1][ejj][eb];
                    gg += glp[w][2][ejj][eb]; go += glp[w][3][ejj][eb];
                }
                const float hn = lstm_cell(gi, gf, gg, go, c);
                bl0[eb][jb + ejj] = (f16)hn;          // own seg for step t+1
                const float ho = __shfl_xor(hn, 1);
                if (!(ejj & 1))
                    ast64(h0i + (size_t)(t & 3) * 2048 + mem * 64 + eb * 8 + (ejj >> 1),
                          pack_h(hn, ho, (uint32_t)(t + 1)));
            }
        }
    } else {
        // ---- layer 1: Whh1 + Wih1, both K=512
        half8 ah[4][4], ai[4][4];
        {
            const int kb = wave * 128 + quad * 8;
#pragma unroll
            for (int gt = 0; gt < 4; ++gt) {
                const f16* wr = Whh1 + (size_t)(gt * 512 + jb + lm) * H_ + kb;
                const f16* xr = Wih1 + (size_t)(gt * 512 + jb + lm) * H_ + kb;
#pragma unroll
                for (int kk = 0; kk < 4; ++kk) {
                    ah[gt][kk] = *(const half8*)(wr + kk * 32);
                    ai[gt][kk] = *(const half8*)(xr + kk * 32);
                }
            }
        }
        float bias[4];
#pragma unroll
        for (int g = 0; g < 4; ++g) bias[g] = bs1[g * 512 + jb + ejj];
        float c = 0.f;

        for (int t = 0; t < T_; ++t) {
            uint32_t fv = 0;
            if (wave == 0) fv = ald(fp);
            // ---- stage h1[t-1] (tag t, slot (t-1)&3) + h0[t] (tag t+1, slot t&3)
            const u64* sp1 = h1i + (size_t)((t + 3) & 3) * 2048;
            const u64* sp0 = h0i + (size_t)(t & 3) * 2048;
            u64 v1[8], v0[8];
#pragma unroll
            for (int i = 0; i < 8; ++i) v1[i] = ald64(sp1 + i * 256 + tid);
#pragma unroll
            for (int i = 0; i < 8; ++i) v0[i] = ald64(sp0 + i * 256 + tid);
            const uint32_t e1 = (uint32_t)t, e0 = (uint32_t)(t + 1);
#pragma unroll
            for (int i = 0; i < 8; ++i) {
                const int f = i * 256 + tid;
                if ((f >> 6) != mem) {
                    while ((uint32_t)(v1[i] >> 32) != e1) v1[i] = ald64(sp1 + f);
                    *(uint32_t*)&bl0[(f >> 3) & 7][((f >> 6) << 4) + ((f & 7) << 1)]
                        = (uint32_t)v1[i];
                }
                while ((uint32_t)(v0[i] >> 32) != e0) v0[i] = ald64(sp0 + f);
                *(uint32_t*)&bl1[(f >> 3) & 7][((f >> 6) << 4) + ((f & 7) << 1)]
                    = (uint32_t)v0[i];
            }
            __syncthreads();
            if (tid == 0) ast(myF, (uint32_t)(t + 1));
            floatx4 acc[4] = {};
            {
                const f16* br0 = &bl0[hrow][wave * 128 + quad * 8];
                const f16* br1 = &bl1[hrow][wave * 128 + quad * 8];
#pragma unroll
                for (int kk = 0; kk < 4; ++kk) {
                    const half8 b0v = *(const half8*)(br0 + kk * 32);
                    const half8 b1v = *(const half8*)(br1 + kk * 32);
#pragma unroll
                    for (int gt = 0; gt < 4; ++gt) {
                        acc[gt] = __builtin_amdgcn_mfma_f32_16x16x32_f16(
                            ah[gt][kk], b0v, acc[gt], 0, 0, 0);
                        acc[gt] = __builtin_amdgcn_mfma_f32_16x16x32_f16(
                            ai[gt][kk], b1v, acc[gt], 0, 0, 0);
                    }
                }
            }
            if (lm < 8)
#pragma unroll
                for (int gt = 0; gt < 4; ++gt)
#pragma unroll
                    for (int r = 0; r < 4; ++r)
                        glp[wave][gt][quad * 4 + r][lm] = acc[gt][r];
            // ---- back-pressure verify: L1 peers >= t-2
            if (wave == 0) {
                const int ti = t - 2;
                const uint32_t tgt = ti < 0 ? 0u : (uint32_t)ti;
                while (!__all((int)(fv >= tgt))) fv = ald(fp);
            }
            __syncthreads();
            if (tid < 128) {
                float gi = bias[0], gf = bias[1], gg = bias[2], go = bias[3];
#pragma unroll
                for (int w = 0; w < 4; ++w) {
                    gi += glp[w][0][ejj][eb]; gf += glp[w][1][ejj][eb];
                    gg += glp[w][2][ejj][eb]; go += glp[w][3][ejj][eb];
                }
                const float hn = lstm_cell(gi, gf, gg, go, c);
                bl0[eb][jb + ejj] = (f16)hn;
                const float ho = __shfl_xor(hn, 1);
                if (!(ejj & 1))
                    ast64(h1i + (size_t)(t & 3) * 2048 + mem * 64 + eb * 8 + (ejj >> 1),
                          pack_h(hn, ho, (uint32_t)(t + 1)));
                if (t == T_ - 1)
                    dout[(size_t)(b0 + eb) * H_ + jb + ejj] = hn;
            }
        }
    }
}

// ------------------------------------------------------------ launcher ------
extern "C" void kernel_launch(void* const* d_in, const int* in_sizes, int n_in,
                              void* d_out, int out_size, void* d_ws, size_t ws_size,
                              hipStream_t stream) {
    const float* x    = (const float*)d_in[0];
    const float* Wih0 = (const float*)d_in[1];
    const float* Whh0 = (const float*)d_in[2];
    const float* bih0 = (const float*)d_in[3];
    const float* bhh0 = (const float*)d_in[4];
    const float* mih0 = (const float*)d_in[5];
    const float* mhh0 = (const float*)d_in[6];
    const float* Wih1 = (const float*)d_in[7];
    const float* Whh1 = (const float*)d_in[8];
    const float* bih1 = (const float*)d_in[9];
    const float* bhh1 = (const float*)d_in[10];
    const float* mih1 = (const float*)d_in[11];
    const float* mhh1 = (const float*)d_in[12];

    char* ws = (char*)d_ws;
    uint32_t* flags = (uint32_t*)(ws + OFF_FLAGS);
    u64* h0b = (u64*)(ws + OFF_H0B);
    u64* h1b = (u64*)(ws + OFF_H1B);
    f16*   wih0 = (f16*)(ws + OFF_WIH0);
    f16*   whh0 = (f16*)(ws + OFF_WHH0);
    f16*   wih1 = (f16*)(ws + OFF_WIH1);
    f16*   whh1 = (f16*)(ws + OFF_WHH1);
    float* bs0  = (float*)(ws + OFF_B0);
    float* bs1  = (float*)(ws + OFF_B1);
    float* out  = (float*)d_out;

    // zero flags + rings (tags must start at 0; ws is re-poisoned every call)
    hipMemsetAsync(ws, 0, ZERO_BYTES, stream);

    k_maskw<<<512,  256, 0, stream>>>(Wih0, mih0, wih0, G_ * DIN_ / 4);
    k_maskw<<<1024, 256, 0, stream>>>(Whh0, mhh0, whh0, G_ * H_ / 4);
    k_maskw<<<1024, 256, 0, stream>>>(Wih1, mih1, wih1, G_ * H_ / 4);
    k_maskw<<<1024, 256, 0, stream>>>(Whh1, mhh1, whh1, G_ * H_ / 4);
    k_bias<<<8, 256, 0, stream>>>(bih0, bhh0, bs0);
    k_bias<<<8, 256, 0, stream>>>(bih1, bhh1, bs1);

    fused_rnn<<<512, 256, 0, stream>>>(x, wih0, whh0, bs0, wih1, whh1, bs1,
                                       out, h0b, h1b, flags);

    (void)in_sizes; (void)n_in; (void)out_size; (void)ws_size;
}